// Round 2
// baseline (786.095 us; speedup 1.0000x reference)
//
#include <hip/hip_runtime.h>
#include <hip/hip_bf16.h>

#define NSEG 512
#define HID 768

// ---------------- index compose: out[b,n] = prev[b, inv[b,n]] ----------------
__global__ __launch_bounds__(256)
void compose_k(int* __restrict__ out, const int* __restrict__ inv,
               const int* __restrict__ prev, int N, int Nprev, int total) {
  int t = blockIdx.x * 256 + threadIdx.x;
  if (t >= total) return;
  int b = (t >= N) ? 1 : 0;              // B == 2
  out[t] = prev[b * Nprev + inv[t]];
}

// ---------------- histogram of segment ids ----------------
__global__ __launch_bounds__(256)
void hist_k(int* __restrict__ cnt, const int* __restrict__ p2s, int N, int total) {
  int t = blockIdx.x * 256 + threadIdx.x;
  if (t >= total) return;
  int b = (t >= N) ? 1 : 0;
  atomicAdd(&cnt[b * NSEG + p2s[t]], 1);
}

// ---------------- per-(level,batch) exclusive scan over 512 counts ----------------
__global__ __launch_bounds__(512)
void scan_k(const int* __restrict__ cnt, int* __restrict__ off) {
  __shared__ int sm[NSEG];
  int base = blockIdx.x * NSEG;
  int t = threadIdx.x;
  int v = cnt[base + t];
  sm[t] = v;
  __syncthreads();
  for (int d = 1; d < NSEG; d <<= 1) {
    int u = (t >= d) ? sm[t - d] : 0;
    __syncthreads();
    sm[t] += u;
    __syncthreads();
  }
  off[base + t] = sm[t] - v;
}

// ---------------- scatter point ids into per-segment lists ----------------
__global__ __launch_bounds__(256)
void scat_k(int* __restrict__ pt, int* __restrict__ cur, const int* __restrict__ off,
            const int* __restrict__ p2s, int N, int total) {
  int t = blockIdx.x * 256 + threadIdx.x;
  if (t >= total) return;
  int b = (t >= N) ? 1 : 0;
  int n = t - b * N;
  int idx = b * NSEG + p2s[t];
  int pos = off[idx] + atomicAdd(&cur[idx], 1);
  pt[b * N + pos] = n;
}

// ---------------- segment-major mean over cascaded (gathered) feature blocks ----------------
struct RedArgs {
  const float* x[5];   // native features, list order: j = i, i-1, ..., 0
  const int*   ci[5];  // composed index maps (nullptr => identity)
  int Nj[5];
  int CN[5];
  int OFF[5];          // column offset of block within C_full (ascending in list order)
  int nb;              // i+1 blocks
  int N;               // N_i
  int CF;              // C_full_i
};

__global__ __launch_bounds__(256)
void reduce_k(RedArgs a, const int* __restrict__ pt, const int* __restrict__ cnt,
              const int* __restrict__ off, float* __restrict__ seg) {
  int bs = blockIdx.x;          // b*512 + s
  int b  = bs >> 9;
  int t  = threadIdx.x;

  const float* xs[5];
  const int*   cim[5];
  int str[5];
  bool val[5];
#pragma unroll
  for (int k = 0; k < 5; k++) {
    int c = t + k * 256;
    val[k] = (c < a.CF);
    xs[k] = nullptr; cim[k] = nullptr; str[k] = 1;
    if (val[k]) {
      int j = 0;
      while (j < a.nb - 1 && !(c >= a.OFF[j] && c < a.OFF[j] + a.CN[j])) j++;
      xs[k]  = a.x[j] + (size_t)b * a.Nj[j] * a.CN[j] + (c - a.OFF[j]);
      cim[k] = a.ci[j] ? (a.ci[j] + (size_t)b * a.N) : nullptr;
      str[k] = a.CN[j];
    }
  }

  int m  = cnt[bs];
  int o0 = off[bs];
  const int* pl = pt + (size_t)b * a.N;

  float acc[5] = {0.f, 0.f, 0.f, 0.f, 0.f};
  for (int p = 0; p < m; p++) {
    int n = pl[o0 + p];
#pragma unroll
    for (int k = 0; k < 5; k++) {
      if (val[k]) {
        int row = cim[k] ? cim[k][n] : n;
        acc[k] += xs[k][(size_t)row * str[k]];
      }
    }
  }
  float sc = 1.0f / (float)(m > 0 ? m : 1);
#pragma unroll
  for (int k = 0; k < 5; k++)
    if (val[k]) seg[(size_t)bs * a.CF + t + k * 256] = acc[k] * sc;
}

// ---------------- fp32 tiled GEMM: proj[lvl] = seg[lvl] @ W[lvl] + bias ----------------
struct GemmArgs {
  const float* S[5];
  const float* W[5];
  const float* bias[5];
  int K[5];
  float* proj;
};

__global__ __launch_bounds__(256)
void gemm_k(GemmArgs ga) {
  int lvl = blockIdx.z;
  const float* __restrict__ S    = ga.S[lvl];
  const float* __restrict__ W    = ga.W[lvl];
  const float* __restrict__ bias = ga.bias[lvl];
  int K  = ga.K[lvl];
  int m0 = blockIdx.y * 64;
  int n0 = blockIdx.x * 64;

  __shared__ float As[32][68];   // As[k][m], padded stride
  __shared__ float Bs[32][64];   // Bs[k][n]

  int tx = threadIdx.x, ty = threadIdx.y;
  int tid = ty * 16 + tx;
  float acc[4][4] = {};

  for (int k0 = 0; k0 < K; k0 += 32) {
#pragma unroll
    for (int it = 0; it < 2; it++) {
      int f = tid + it * 256;
      // A tile: 64 rows x 32 k
      int row = f >> 3;
      int kq  = f & 7;
      int kk  = k0 + kq * 4;
      float4 v = make_float4(0.f, 0.f, 0.f, 0.f);
      if (kk < K) v = *(const float4*)&S[(size_t)(m0 + row) * K + kk];
      As[kq * 4 + 0][row] = v.x;
      As[kq * 4 + 1][row] = v.y;
      As[kq * 4 + 2][row] = v.z;
      As[kq * 4 + 3][row] = v.w;
      // B tile: 32 k x 64 n
      int kr = f >> 4;
      int nq = f & 15;
      int k2 = k0 + kr;
      float4 w = make_float4(0.f, 0.f, 0.f, 0.f);
      if (k2 < K) w = *(const float4*)&W[(size_t)k2 * HID + n0 + nq * 4];
      *(float4*)&Bs[kr][nq * 4] = w;
    }
    __syncthreads();
#pragma unroll
    for (int kk = 0; kk < 32; kk++) {
      float4 a4 = *(const float4*)&As[kk][ty * 4];
      float4 b4 = *(const float4*)&Bs[kk][tx * 4];
      float av[4] = {a4.x, a4.y, a4.z, a4.w};
      float bv[4] = {b4.x, b4.y, b4.z, b4.w};
#pragma unroll
      for (int i = 0; i < 4; i++)
#pragma unroll
        for (int j = 0; j < 4; j++) acc[i][j] += av[i] * bv[j];
    }
    __syncthreads();
  }

#pragma unroll
  for (int i = 0; i < 4; i++) {
    int r = lvl * 1024 + m0 + ty * 4 + i;
#pragma unroll
    for (int j = 0; j < 4; j++) {
      int cidx = n0 + tx * 4 + j;
      ga.proj[(size_t)r * HID + cidx] = acc[i][j] + bias[cidx];
    }
  }
}

// ---------------- LayerNorm over HID=768, write float32 ----------------
struct LnArgs { const float* g[5]; const float* be[5]; };

__global__ __launch_bounds__(256)
void ln_k(LnArgs la, const float* __restrict__ proj, float* __restrict__ out) {
  int row = blockIdx.x;           // 0..5119 = lvl*1024 + b*512 + s
  int lvl = row >> 10;
  const float* x = proj + (size_t)row * HID;
  int t = threadIdx.x;
  float v0 = x[t], v1 = x[t + 256], v2 = x[t + 512];
  float s = v0 + v1 + v2;
  float q = v0 * v0 + v1 * v1 + v2 * v2;
#pragma unroll
  for (int d = 32; d >= 1; d >>= 1) { s += __shfl_down(s, d); q += __shfl_down(q, d); }
  __shared__ float ps[4], pq[4];
  int w = t >> 6;
  if ((t & 63) == 0) { ps[w] = s; pq[w] = q; }
  __syncthreads();
  float S = ps[0] + ps[1] + ps[2] + ps[3];
  float Q = pq[0] + pq[1] + pq[2] + pq[3];
  float mean = S * (1.0f / HID);
  float var  = Q * (1.0f / HID) - mean * mean;
  float rs   = rsqrtf(var + 1e-5f);
  const float* g  = la.g[lvl];
  const float* be = la.be[lvl];
  float* o = out + (size_t)row * HID;
  o[t]       = (v0 - mean) * rs * g[t]       + be[t];
  o[t + 256] = (v1 - mean) * rs * g[t + 256] + be[t + 256];
  o[t + 512] = (v2 - mean) * rs * g[t + 512] + be[t + 512];
}

// =====================================================================
extern "C" void kernel_launch(void* const* d_in, const int* in_sizes, int n_in,
                              void* d_out, int out_size, void* d_ws, size_t ws_size,
                              hipStream_t stream) {
  static const int N_[5]  = {256, 1024, 4096, 16384, 65536};
  static const int CN_[5] = {512, 384, 192, 96, 48};
  static const int CF_[5] = {512, 896, 1088, 1184, 1232};

  const float* x[5]; const int* p2s[5]; const float* W[5];
  const float* bias[5]; const float* g[5]; const float* be[5];
  for (int i = 0; i < 5; i++) {
    x[i]    = (const float*)d_in[6 * i + 0];
    p2s[i]  = (const int*)  d_in[6 * i + 1];
    W[i]    = (const float*)d_in[6 * i + 2];
    bias[i] = (const float*)d_in[6 * i + 3];
    g[i]    = (const float*)d_in[6 * i + 4];
    be[i]   = (const float*)d_in[6 * i + 5];
  }
  const int* inv[5] = {nullptr, (const int*)d_in[30], (const int*)d_in[31],
                       (const int*)d_in[32], (const int*)d_in[33]};

  int*   wsi = (int*)d_ws;
  float* wsf = (float*)d_ws;

  // workspace layout (4-byte element offsets)
  const int CNT = 0;          // 5*2*512
  const int CUR = 5120;
  const int OFS = 10240;
  int PT[5]; { int a = 15360; for (int i = 0; i < 5; i++) { PT[i] = a; a += 2 * N_[i]; } }
  const int CI20 = 189952, CI31 = 198144, CI30 = 230912;
  const int CI42 = 263680, CI41 = 394752, CI40 = 525824;
  int SG[5]; { int a = 656896; for (int i = 0; i < 5; i++) { SG[i] = a; a += 2 * NSEG * CF_[i]; } }
  const int PROJ = 5686784;   // 5*1024*768 floats; ws end = 9618944 elems (~38.5 MB)

  hipMemsetAsync(wsi + CNT, 0, (size_t)10240 * 4, stream);   // cnt + cur

  auto nb = [](int tot) { return (tot + 255) / 256; };
  // composed index maps (order matters: ci3_* needs ci2_0, ci4_* needs ci3_*)
  compose_k<<<nb(2 * 4096),  256, 0, stream>>>(wsi + CI20, inv[2], inv[1],      4096, 1024,  2 * 4096);
  compose_k<<<nb(2 * 16384), 256, 0, stream>>>(wsi + CI31, inv[3], inv[2],      16384, 4096, 2 * 16384);
  compose_k<<<nb(2 * 16384), 256, 0, stream>>>(wsi + CI30, inv[3], wsi + CI20,  16384, 4096, 2 * 16384);
  compose_k<<<nb(2 * 65536), 256, 0, stream>>>(wsi + CI42, inv[4], inv[3],      65536, 16384, 2 * 65536);
  compose_k<<<nb(2 * 65536), 256, 0, stream>>>(wsi + CI41, inv[4], wsi + CI31,  65536, 16384, 2 * 65536);
  compose_k<<<nb(2 * 65536), 256, 0, stream>>>(wsi + CI40, inv[4], wsi + CI30,  65536, 16384, 2 * 65536);

  for (int i = 0; i < 5; i++)
    hist_k<<<nb(2 * N_[i]), 256, 0, stream>>>(wsi + CNT + i * 1024, p2s[i], N_[i], 2 * N_[i]);

  scan_k<<<10, 512, 0, stream>>>(wsi + CNT, wsi + OFS);

  for (int i = 0; i < 5; i++)
    scat_k<<<nb(2 * N_[i]), 256, 0, stream>>>(wsi + PT[i], wsi + CUR + i * 1024,
                                              wsi + OFS + i * 1024, p2s[i], N_[i], 2 * N_[i]);

  // composed-map table
  const int* cimap[5][5] = {};
  cimap[1][0] = inv[1];
  cimap[2][1] = inv[2]; cimap[2][0] = wsi + CI20;
  cimap[3][2] = inv[3]; cimap[3][1] = wsi + CI31; cimap[3][0] = wsi + CI30;
  cimap[4][3] = inv[4]; cimap[4][2] = wsi + CI42; cimap[4][1] = wsi + CI41; cimap[4][0] = wsi + CI40;

  int offs[5][5] = {};
  for (int i = 1; i < 5; i++)
    for (int j = i - 1; j >= 0; j--) offs[i][j] = CN_[i] + offs[i - 1][j];

  for (int i = 0; i < 5; i++) {
    RedArgs ra{};
    int d = 0;
    for (int j = i; j >= 0; j--) {
      ra.x[d]   = x[j];
      ra.ci[d]  = (j == i) ? nullptr : cimap[i][j];
      ra.Nj[d]  = N_[j];
      ra.CN[d]  = CN_[j];
      ra.OFF[d] = offs[i][j];
      d++;
    }
    ra.nb = d; ra.N = N_[i]; ra.CF = CF_[i];
    reduce_k<<<1024, 256, 0, stream>>>(ra, wsi + PT[i], wsi + CNT + i * 1024,
                                       wsi + OFS + i * 1024, wsf + SG[i]);
  }

  GemmArgs ga{};
  for (int i = 0; i < 5; i++) { ga.S[i] = wsf + SG[i]; ga.W[i] = W[i]; ga.bias[i] = bias[i]; ga.K[i] = CF_[i]; }
  ga.proj = wsf + PROJ;
  gemm_k<<<dim3(12, 16, 5), dim3(16, 16), 0, stream>>>(ga);

  LnArgs la{};
  for (int i = 0; i < 5; i++) { la.g[i] = g[i]; la.be[i] = be[i]; }
  ln_k<<<5120, 256, 0, stream>>>(la, wsf + PROJ, (float*)d_out);
}

// Round 3
// 490.332 us; speedup vs baseline: 1.6032x; 1.6032x over previous
//
#include <hip/hip_runtime.h>
#include <hip/hip_bf16.h>

#define NSEG 512
#define HID 768

// ---------------- fused index-compose chains ----------------
__global__ __launch_bounds__(256)
void compose4_k(int* __restrict__ c42, int* __restrict__ c41, int* __restrict__ c40,
                const int* __restrict__ inv4, const int* __restrict__ inv3,
                const int* __restrict__ inv2, const int* __restrict__ inv1, int total) {
  int t = blockIdx.x * 256 + threadIdx.x;
  if (t >= total) return;
  int b = (t >= 65536) ? 1 : 0;
  int n3 = inv4[t];
  int n2 = inv3[b * 16384 + n3]; c42[t] = n2;
  int n1 = inv2[b * 4096  + n2]; c41[t] = n1;
  int n0 = inv1[b * 1024  + n1]; c40[t] = n0;
}

__global__ __launch_bounds__(256)
void compose3_k(int* __restrict__ c31, int* __restrict__ c30,
                const int* __restrict__ inv3, const int* __restrict__ inv2,
                const int* __restrict__ inv1, int total) {
  int t = blockIdx.x * 256 + threadIdx.x;
  if (t >= total) return;
  int b = (t >= 16384) ? 1 : 0;
  int n2 = inv3[t];
  int n1 = inv2[b * 4096 + n2]; c31[t] = n1;
  int n0 = inv1[b * 1024 + n1]; c30[t] = n0;
}

__global__ __launch_bounds__(256)
void compose2_k(int* __restrict__ c20, const int* __restrict__ inv2,
                const int* __restrict__ inv1, int total) {
  int t = blockIdx.x * 256 + threadIdx.x;
  if (t >= total) return;
  int b = (t >= 4096) ? 1 : 0;
  c20[t] = inv1[b * 1024 + inv2[t]];
}

// ---------------- histogram of segment ids ----------------
__global__ __launch_bounds__(256)
void hist_k(int* __restrict__ cnt, const int* __restrict__ p2s, int N, int total) {
  int t = blockIdx.x * 256 + threadIdx.x;
  if (t >= total) return;
  int b = (t >= N) ? 1 : 0;
  atomicAdd(&cnt[b * NSEG + p2s[t]], 1);
}

// ---------------- per-(level,batch) exclusive scan + 1/m ----------------
__global__ __launch_bounds__(512)
void scan_k(const int* __restrict__ cnt, int* __restrict__ off, float* __restrict__ scl) {
  __shared__ int sm[NSEG];
  int base = blockIdx.x * NSEG;
  int t = threadIdx.x;
  int v = cnt[base + t];
  sm[t] = v;
  __syncthreads();
  for (int d = 1; d < NSEG; d <<= 1) {
    int u = (t >= d) ? sm[t - d] : 0;
    __syncthreads();
    sm[t] += u;
    __syncthreads();
  }
  off[base + t] = sm[t] - v;
  scl[base + t] = 1.0f / (float)(v > 0 ? v : 1);
}

// ---------------- scatter point ids into per-segment lists ----------------
__global__ __launch_bounds__(256)
void scat_k(int* __restrict__ pt, int* __restrict__ cur, const int* __restrict__ off,
            const int* __restrict__ p2s, int N, int total) {
  int t = blockIdx.x * 256 + threadIdx.x;
  if (t >= total) return;
  int b = (t >= N) ? 1 : 0;
  int n = t - b * N;
  int idx = b * NSEG + p2s[t];
  int pos = off[idx] + atomicAdd(&cur[idx], 1);
  pt[b * N + pos] = n;
}

// ---------------- segment-major SUM over cascaded feature blocks ----------------
// Each thread owns float4 channel-groups (all concat offsets are x16 floats -> aligned).
// CHUNKED: point list split across gridDim.y blocks, partials atomicAdd'ed into
// pre-zeroed seg. Scaling by 1/m is folded into the GEMM A-load.
struct RedArgs {
  const float* x[5];   // list order: j = i, i-1, ..., 0
  const int*   ci[5];  // composed maps (nullptr => identity)
  int Nj[5];
  int CN[5];
  int OFF[5];          // column offset (floats) of block within C_full
  int nb;
  int N;               // N_i
  int CF;              // C_full_i
};

template<int NK, bool CHUNKED>
__global__ __launch_bounds__(256)
void reduce2_k(RedArgs a, const int* __restrict__ pt, const int* __restrict__ cnt,
               const int* __restrict__ off, float* __restrict__ seg, int nchunk) {
  int bs = blockIdx.x;          // b*512 + s
  int b  = bs >> 9;
  int t  = threadIdx.x;
  int m  = cnt[bs];

  // group -> (block j, base ptr, stride) mapping, once per thread
  const float* xs[NK]; const int* cim[NK]; int str[NK]; bool val[NK];
#pragma unroll
  for (int k = 0; k < NK; k++) {
    int c4 = (t + k * 256) * 4;
    val[k] = c4 < a.CF;
    xs[k] = nullptr; cim[k] = nullptr; str[k] = 1;
    if (val[k]) {
      int j = 0;
      while (j < a.nb - 1 && !(c4 >= a.OFF[j] && c4 < a.OFF[j] + a.CN[j])) j++;
      xs[k]  = a.x[j] + (size_t)b * a.Nj[j] * a.CN[j] + (c4 - a.OFF[j]);
      cim[k] = a.ci[j] ? (a.ci[j] + (size_t)b * a.N) : nullptr;
      str[k] = a.CN[j];
    }
  }

  int start = 0, end = m;
  if (CHUNKED) {
    int cs = (m + nchunk - 1) / nchunk;
    start = blockIdx.y * cs;
    end = min(m, start + cs);
    if (start >= end) return;            // seg pre-zeroed
  } else {
    if (m == 0) {                        // write zeros (region not memset)
      float* so = seg + (size_t)bs * a.CF;
#pragma unroll
      for (int k = 0; k < NK; k++)
        if (val[k]) *(float4*)(so + (t + k * 256) * 4) = make_float4(0.f, 0.f, 0.f, 0.f);
      return;
    }
  }

  const int* pl = pt + (size_t)b * a.N + off[bs];
  float ax[NK][4] = {};
  int p = start;
  for (; p + 4 <= end; p += 4) {
    int n0 = pl[p], n1 = pl[p + 1], n2 = pl[p + 2], n3 = pl[p + 3];
#pragma unroll
    for (int k = 0; k < NK; k++) if (val[k]) {
      int r0 = cim[k] ? cim[k][n0] : n0;
      int r1 = cim[k] ? cim[k][n1] : n1;
      int r2 = cim[k] ? cim[k][n2] : n2;
      int r3 = cim[k] ? cim[k][n3] : n3;
      float4 v0 = *(const float4*)(xs[k] + (size_t)r0 * str[k]);
      float4 v1 = *(const float4*)(xs[k] + (size_t)r1 * str[k]);
      float4 v2 = *(const float4*)(xs[k] + (size_t)r2 * str[k]);
      float4 v3 = *(const float4*)(xs[k] + (size_t)r3 * str[k]);
      ax[k][0] += (v0.x + v1.x) + (v2.x + v3.x);
      ax[k][1] += (v0.y + v1.y) + (v2.y + v3.y);
      ax[k][2] += (v0.z + v1.z) + (v2.z + v3.z);
      ax[k][3] += (v0.w + v1.w) + (v2.w + v3.w);
    }
  }
  for (; p < end; p++) {
    int n0 = pl[p];
#pragma unroll
    for (int k = 0; k < NK; k++) if (val[k]) {
      int r0 = cim[k] ? cim[k][n0] : n0;
      float4 v0 = *(const float4*)(xs[k] + (size_t)r0 * str[k]);
      ax[k][0] += v0.x; ax[k][1] += v0.y; ax[k][2] += v0.z; ax[k][3] += v0.w;
    }
  }

  float* so = seg + (size_t)bs * a.CF;
#pragma unroll
  for (int k = 0; k < NK; k++) if (val[k]) {
    int c4 = (t + k * 256) * 4;
    if (CHUNKED) {
      atomicAdd(&so[c4 + 0], ax[k][0]);
      atomicAdd(&so[c4 + 1], ax[k][1]);
      atomicAdd(&so[c4 + 2], ax[k][2]);
      atomicAdd(&so[c4 + 3], ax[k][3]);
    } else {
      *(float4*)(so + c4) = make_float4(ax[k][0], ax[k][1], ax[k][2], ax[k][3]);
    }
  }
}

// ---------------- fp32 tiled GEMM: proj = (seg * scl_row) @ W + bias ----------------
struct GemmArgs {
  const float* S[5];
  const float* W[5];
  const float* bias[5];
  const float* scl;     // [5*1024] per-row 1/m
  int K[5];
  float* proj;
};

__global__ __launch_bounds__(256)
void gemm_k(GemmArgs ga) {
  int lvl = blockIdx.z;
  const float* __restrict__ S    = ga.S[lvl];
  const float* __restrict__ W    = ga.W[lvl];
  const float* __restrict__ bias = ga.bias[lvl];
  const float* __restrict__ scl  = ga.scl + lvl * 1024;
  int K  = ga.K[lvl];
  int m0 = blockIdx.y * 64;
  int n0 = blockIdx.x * 64;

  __shared__ float As[32][68];
  __shared__ float Bs[32][64];

  int tx = threadIdx.x, ty = threadIdx.y;
  int tid = ty * 16 + tx;
  float acc[4][4] = {};

  for (int k0 = 0; k0 < K; k0 += 32) {
#pragma unroll
    for (int it = 0; it < 2; it++) {
      int f = tid + it * 256;
      int row = f >> 3;
      int kq  = f & 7;
      int kk  = k0 + kq * 4;
      float4 v = make_float4(0.f, 0.f, 0.f, 0.f);
      if (kk < K) v = *(const float4*)&S[(size_t)(m0 + row) * K + kk];
      float srow = scl[m0 + row];
      As[kq * 4 + 0][row] = v.x * srow;
      As[kq * 4 + 1][row] = v.y * srow;
      As[kq * 4 + 2][row] = v.z * srow;
      As[kq * 4 + 3][row] = v.w * srow;
      int kr = f >> 4;
      int nq = f & 15;
      int k2 = k0 + kr;
      float4 w = make_float4(0.f, 0.f, 0.f, 0.f);
      if (k2 < K) w = *(const float4*)&W[(size_t)k2 * HID + n0 + nq * 4];
      *(float4*)&Bs[kr][nq * 4] = w;
    }
    __syncthreads();
#pragma unroll
    for (int kk = 0; kk < 32; kk++) {
      float4 a4 = *(const float4*)&As[kk][ty * 4];
      float4 b4 = *(const float4*)&Bs[kk][tx * 4];
      float av[4] = {a4.x, a4.y, a4.z, a4.w};
      float bv[4] = {b4.x, b4.y, b4.z, b4.w};
#pragma unroll
      for (int i = 0; i < 4; i++)
#pragma unroll
        for (int j = 0; j < 4; j++) acc[i][j] += av[i] * bv[j];
    }
    __syncthreads();
  }

#pragma unroll
  for (int i = 0; i < 4; i++) {
    int r = lvl * 1024 + m0 + ty * 4 + i;
#pragma unroll
    for (int j = 0; j < 4; j++) {
      int cidx = n0 + tx * 4 + j;
      ga.proj[(size_t)r * HID + cidx] = acc[i][j] + bias[cidx];
    }
  }
}

// ---------------- LayerNorm over HID=768, write float32 ----------------
struct LnArgs { const float* g[5]; const float* be[5]; };

__global__ __launch_bounds__(256)
void ln_k(LnArgs la, const float* __restrict__ proj, float* __restrict__ out) {
  int row = blockIdx.x;
  int lvl = row >> 10;
  const float* x = proj + (size_t)row * HID;
  int t = threadIdx.x;
  float v0 = x[t], v1 = x[t + 256], v2 = x[t + 512];
  float s = v0 + v1 + v2;
  float q = v0 * v0 + v1 * v1 + v2 * v2;
#pragma unroll
  for (int d = 32; d >= 1; d >>= 1) { s += __shfl_down(s, d); q += __shfl_down(q, d); }
  __shared__ float ps[4], pq[4];
  int w = t >> 6;
  if ((t & 63) == 0) { ps[w] = s; pq[w] = q; }
  __syncthreads();
  float S = ps[0] + ps[1] + ps[2] + ps[3];
  float Q = pq[0] + pq[1] + pq[2] + pq[3];
  float mean = S * (1.0f / HID);
  float var  = Q * (1.0f / HID) - mean * mean;
  float rs   = rsqrtf(var + 1e-5f);
  const float* g  = la.g[lvl];
  const float* be = la.be[lvl];
  float* o = out + (size_t)row * HID;
  o[t]       = (v0 - mean) * rs * g[t]       + be[t];
  o[t + 256] = (v1 - mean) * rs * g[t + 256] + be[t + 256];
  o[t + 512] = (v2 - mean) * rs * g[t + 512] + be[t + 512];
}

// =====================================================================
extern "C" void kernel_launch(void* const* d_in, const int* in_sizes, int n_in,
                              void* d_out, int out_size, void* d_ws, size_t ws_size,
                              hipStream_t stream) {
  static const int N_[5]  = {256, 1024, 4096, 16384, 65536};
  static const int CN_[5] = {512, 384, 192, 96, 48};
  static const int CF_[5] = {512, 896, 1088, 1184, 1232};
  static const int NC_[5] = {1, 1, 2, 4, 8};   // point-chunks per segment

  const float* x[5]; const int* p2s[5]; const float* W[5];
  const float* bias[5]; const float* g[5]; const float* be[5];
  for (int i = 0; i < 5; i++) {
    x[i]    = (const float*)d_in[6 * i + 0];
    p2s[i]  = (const int*)  d_in[6 * i + 1];
    W[i]    = (const float*)d_in[6 * i + 2];
    bias[i] = (const float*)d_in[6 * i + 3];
    g[i]    = (const float*)d_in[6 * i + 4];
    be[i]   = (const float*)d_in[6 * i + 5];
  }
  const int* inv[5] = {nullptr, (const int*)d_in[30], (const int*)d_in[31],
                       (const int*)d_in[32], (const int*)d_in[33]};

  int*   wsi = (int*)d_ws;
  float* wsf = (float*)d_ws;

  // workspace layout (4-byte element offsets)
  const int CNT = 0;          // 5*2*512
  const int CUR = 5120;
  const int OFS = 10240;
  int PT[5]; { int a = 15360; for (int i = 0; i < 5; i++) { PT[i] = a; a += 2 * N_[i]; } }
  const int CI20 = 189952, CI31 = 198144, CI30 = 230912;
  const int CI42 = 263680, CI41 = 394752, CI40 = 525824;
  int SG[5]; { int a = 656896; for (int i = 0; i < 5; i++) { SG[i] = a; a += 2 * NSEG * CF_[i]; } }
  const int PROJ = 5686784;   // 5*1024*768 floats
  const int SCL  = 9618944;   // 5120 floats; ws end = 9624064 elems (~38.5 MB)

  hipMemsetAsync(wsi + CNT, 0, (size_t)10240 * 4, stream);                     // cnt + cur
  hipMemsetAsync(wsf + SG[2], 0, (size_t)(PROJ - SG[2]) * 4, stream);          // chunked seg lvls

  auto nb = [](int tot) { return (tot + 255) / 256; };
  compose2_k<<<nb(2 * 4096),  256, 0, stream>>>(wsi + CI20, inv[2], inv[1], 2 * 4096);
  compose3_k<<<nb(2 * 16384), 256, 0, stream>>>(wsi + CI31, wsi + CI30, inv[3], inv[2], inv[1], 2 * 16384);
  compose4_k<<<nb(2 * 65536), 256, 0, stream>>>(wsi + CI42, wsi + CI41, wsi + CI40,
                                                inv[4], inv[3], inv[2], inv[1], 2 * 65536);

  for (int i = 0; i < 5; i++)
    hist_k<<<nb(2 * N_[i]), 256, 0, stream>>>(wsi + CNT + i * 1024, p2s[i], N_[i], 2 * N_[i]);

  scan_k<<<10, 512, 0, stream>>>(wsi + CNT, wsi + OFS, wsf + SCL);

  for (int i = 0; i < 5; i++)
    scat_k<<<nb(2 * N_[i]), 256, 0, stream>>>(wsi + PT[i], wsi + CUR + i * 1024,
                                              wsi + OFS + i * 1024, p2s[i], N_[i], 2 * N_[i]);

  const int* cimap[5][5] = {};
  cimap[1][0] = inv[1];
  cimap[2][1] = inv[2]; cimap[2][0] = wsi + CI20;
  cimap[3][2] = inv[3]; cimap[3][1] = wsi + CI31; cimap[3][0] = wsi + CI30;
  cimap[4][3] = inv[4]; cimap[4][2] = wsi + CI42; cimap[4][1] = wsi + CI41; cimap[4][0] = wsi + CI40;

  int offs[5][5] = {};
  for (int i = 1; i < 5; i++)
    for (int j = i - 1; j >= 0; j--) offs[i][j] = CN_[i] + offs[i - 1][j];

  for (int i = 0; i < 5; i++) {
    RedArgs ra{};
    int d = 0;
    for (int j = i; j >= 0; j--) {
      ra.x[d]   = x[j];
      ra.ci[d]  = (j == i) ? nullptr : cimap[i][j];
      ra.Nj[d]  = N_[j];
      ra.CN[d]  = CN_[j];
      ra.OFF[d] = offs[i][j];
      d++;
    }
    ra.nb = d; ra.N = N_[i]; ra.CF = CF_[i];
    dim3 grid(1024, NC_[i]);
    if (i <= 1)
      reduce2_k<1, false><<<grid, 256, 0, stream>>>(ra, wsi + PT[i], wsi + CNT + i * 1024,
                                                    wsi + OFS + i * 1024, wsf + SG[i], NC_[i]);
    else
      reduce2_k<2, true><<<grid, 256, 0, stream>>>(ra, wsi + PT[i], wsi + CNT + i * 1024,
                                                   wsi + OFS + i * 1024, wsf + SG[i], NC_[i]);
  }

  GemmArgs ga{};
  for (int i = 0; i < 5; i++) { ga.S[i] = wsf + SG[i]; ga.W[i] = W[i]; ga.bias[i] = bias[i]; ga.K[i] = CF_[i]; }
  ga.scl = wsf + SCL;
  ga.proj = wsf + PROJ;
  gemm_k<<<dim3(12, 16, 5), dim3(16, 16), 0, stream>>>(ga);

  LnArgs la{};
  for (int i = 0; i < 5; i++) { la.g[i] = g[i]; la.be[i] = be[i]; }
  ln_k<<<5120, 256, 0, stream>>>(la, wsf + PROJ, (float*)d_out);
}

// Round 4
// 407.908 us; speedup vs baseline: 1.9271x; 1.2021x over previous
//
#include <hip/hip_runtime.h>
#include <hip/hip_bf16.h>

#define NSEG 512
#define HID 768

typedef __attribute__((ext_vector_type(8))) short s16x8;
typedef __attribute__((ext_vector_type(8))) unsigned short u16x8;
typedef __attribute__((ext_vector_type(4))) float f32x4;

__device__ __forceinline__ unsigned short f2bf(float x) {
  unsigned u = __builtin_bit_cast(unsigned, x);
  unsigned r = (u + 0x7fff + ((u >> 16) & 1)) >> 16;   // RNE
  return (unsigned short)r;
}

__device__ __forceinline__ void gl_lds16(const void* g, void* l) {
  __builtin_amdgcn_global_load_lds(
      (const __attribute__((address_space(1))) unsigned*)g,
      (__attribute__((address_space(3))) unsigned*)l, 16, 0, 0);
}

// ---------------- fused index-compose chains ----------------
__global__ __launch_bounds__(256)
void compose4_k(int* __restrict__ c42, int* __restrict__ c41, int* __restrict__ c40,
                const int* __restrict__ inv4, const int* __restrict__ inv3,
                const int* __restrict__ inv2, const int* __restrict__ inv1, int total) {
  int t = blockIdx.x * 256 + threadIdx.x;
  if (t >= total) return;
  int b = (t >= 65536) ? 1 : 0;
  int n3 = inv4[t];
  int n2 = inv3[b * 16384 + n3]; c42[t] = n2;
  int n1 = inv2[b * 4096  + n2]; c41[t] = n1;
  int n0 = inv1[b * 1024  + n1]; c40[t] = n0;
}

__global__ __launch_bounds__(256)
void compose3_k(int* __restrict__ c31, int* __restrict__ c30,
                const int* __restrict__ inv3, const int* __restrict__ inv2,
                const int* __restrict__ inv1, int total) {
  int t = blockIdx.x * 256 + threadIdx.x;
  if (t >= total) return;
  int b = (t >= 16384) ? 1 : 0;
  int n2 = inv3[t];
  int n1 = inv2[b * 4096 + n2]; c31[t] = n1;
  int n0 = inv1[b * 1024 + n1]; c30[t] = n0;
}

__global__ __launch_bounds__(256)
void compose2_k(int* __restrict__ c20, const int* __restrict__ inv2,
                const int* __restrict__ inv1, int total) {
  int t = blockIdx.x * 256 + threadIdx.x;
  if (t >= total) return;
  int b = (t >= 4096) ? 1 : 0;
  c20[t] = inv1[b * 1024 + inv2[t]];
}

// ---------------- histogram ----------------
__global__ __launch_bounds__(256)
void hist_k(int* __restrict__ cnt, const int* __restrict__ p2s, int N, int total) {
  int t = blockIdx.x * 256 + threadIdx.x;
  if (t >= total) return;
  int b = (t >= N) ? 1 : 0;
  atomicAdd(&cnt[b * NSEG + p2s[t]], 1);
}

// ---------------- scan + 1/m ----------------
__global__ __launch_bounds__(512)
void scan_k(const int* __restrict__ cnt, int* __restrict__ off, float* __restrict__ scl) {
  __shared__ int sm[NSEG];
  int base = blockIdx.x * NSEG;
  int t = threadIdx.x;
  int v = cnt[base + t];
  sm[t] = v;
  __syncthreads();
  for (int d = 1; d < NSEG; d <<= 1) {
    int u = (t >= d) ? sm[t - d] : 0;
    __syncthreads();
    sm[t] += u;
    __syncthreads();
  }
  off[base + t] = sm[t] - v;
  scl[base + t] = 1.0f / (float)(v > 0 ? v : 1);
}

// ---------------- scatter point ids ----------------
__global__ __launch_bounds__(256)
void scat_k(int* __restrict__ pt, int* __restrict__ cur, const int* __restrict__ off,
            const int* __restrict__ p2s, int N, int total) {
  int t = blockIdx.x * 256 + threadIdx.x;
  if (t >= total) return;
  int b = (t >= N) ? 1 : 0;
  int n = t - b * N;
  int idx = b * NSEG + p2s[t];
  int pos = off[idx] + atomicAdd(&cur[idx], 1);
  pt[b * N + pos] = n;
}

// ---------------- segment-major SUM over cascaded feature blocks ----------------
struct RedArgs {
  const float* x[5];
  const int*   ci[5];
  int Nj[5];
  int CN[5];
  int OFF[5];
  int nb;
  int N;
  int CF;
};

template<int NK, bool CHUNKED>
__global__ __launch_bounds__(256)
void reduce2_k(RedArgs a, const int* __restrict__ pt, const int* __restrict__ cnt,
               const int* __restrict__ off, float* __restrict__ seg, int nchunk) {
  int bs = blockIdx.x;
  int b  = bs >> 9;
  int t  = threadIdx.x;
  int m  = cnt[bs];

  const float* xs[NK]; const int* cim[NK]; int str[NK]; bool val[NK];
#pragma unroll
  for (int k = 0; k < NK; k++) {
    int c4 = (t + k * 256) * 4;
    val[k] = c4 < a.CF;
    xs[k] = nullptr; cim[k] = nullptr; str[k] = 1;
    if (val[k]) {
      int j = 0;
      while (j < a.nb - 1 && !(c4 >= a.OFF[j] && c4 < a.OFF[j] + a.CN[j])) j++;
      xs[k]  = a.x[j] + (size_t)b * a.Nj[j] * a.CN[j] + (c4 - a.OFF[j]);
      cim[k] = a.ci[j] ? (a.ci[j] + (size_t)b * a.N) : nullptr;
      str[k] = a.CN[j];
    }
  }

  int start = 0, end = m;
  if (CHUNKED) {
    int cs = (m + nchunk - 1) / nchunk;
    start = blockIdx.y * cs;
    end = min(m, start + cs);
    if (start >= end) return;
  } else {
    if (m == 0) {
      float* so = seg + (size_t)bs * a.CF;
#pragma unroll
      for (int k = 0; k < NK; k++)
        if (val[k]) *(float4*)(so + (t + k * 256) * 4) = make_float4(0.f, 0.f, 0.f, 0.f);
      return;
    }
  }

  const int* pl = pt + (size_t)b * a.N + off[bs];
  float ax[NK][4] = {};
  int p = start;
  for (; p + 4 <= end; p += 4) {
    int n0 = pl[p], n1 = pl[p + 1], n2 = pl[p + 2], n3 = pl[p + 3];
#pragma unroll
    for (int k = 0; k < NK; k++) if (val[k]) {
      int r0 = cim[k] ? cim[k][n0] : n0;
      int r1 = cim[k] ? cim[k][n1] : n1;
      int r2 = cim[k] ? cim[k][n2] : n2;
      int r3 = cim[k] ? cim[k][n3] : n3;
      float4 v0 = *(const float4*)(xs[k] + (size_t)r0 * str[k]);
      float4 v1 = *(const float4*)(xs[k] + (size_t)r1 * str[k]);
      float4 v2 = *(const float4*)(xs[k] + (size_t)r2 * str[k]);
      float4 v3 = *(const float4*)(xs[k] + (size_t)r3 * str[k]);
      ax[k][0] += (v0.x + v1.x) + (v2.x + v3.x);
      ax[k][1] += (v0.y + v1.y) + (v2.y + v3.y);
      ax[k][2] += (v0.z + v1.z) + (v2.z + v3.z);
      ax[k][3] += (v0.w + v1.w) + (v2.w + v3.w);
    }
  }
  for (; p < end; p++) {
    int n0 = pl[p];
#pragma unroll
    for (int k = 0; k < NK; k++) if (val[k]) {
      int r0 = cim[k] ? cim[k][n0] : n0;
      float4 v0 = *(const float4*)(xs[k] + (size_t)r0 * str[k]);
      ax[k][0] += v0.x; ax[k][1] += v0.y; ax[k][2] += v0.z; ax[k][3] += v0.w;
    }
  }

  float* so = seg + (size_t)bs * a.CF;
#pragma unroll
  for (int k = 0; k < NK; k++) if (val[k]) {
    int c4 = (t + k * 256) * 4;
    if (CHUNKED) {
      atomicAdd(&so[c4 + 0], ax[k][0]);
      atomicAdd(&so[c4 + 1], ax[k][1]);
      atomicAdd(&so[c4 + 2], ax[k][2]);
      atomicAdd(&so[c4 + 3], ax[k][3]);
    } else {
      *(float4*)(so + c4) = make_float4(ax[k][0], ax[k][1], ax[k][2], ax[k][3]);
    }
  }
}

// ---------------- seg fp32 -> bf16, scaled by 1/m, chunk-swizzled, K-padded ----------------
// stored chunk c (16B) of row r = orig chunk (c&7)^(r&7) within each 64-elem k-block
struct CsArgs { const float* sg[5]; unsigned short* sb[5]; const float* scl; int CF[5]; int KP[5]; };

__global__ __launch_bounds__(256)
void conv_seg_k(CsArgs a) {
  int row = blockIdx.x;            // 0..5119
  int lvl = row >> 10;
  int rl  = row & 1023;
  int CF = a.CF[lvl], KP = a.KP[lvl];
  int c = threadIdx.x;
  if (c >= (KP >> 3)) return;
  float s = a.scl[row];
  int w = c & 7, blk = c >> 3;
  int k0 = blk * 64 + ((w ^ (rl & 7)) << 3);
  u16x8 o = {0, 0, 0, 0, 0, 0, 0, 0};
  if (k0 < CF) {
    const float* src = a.sg[lvl] + (size_t)rl * CF + k0;
    float4 v0 = *(const float4*)src;
    float4 v1 = *(const float4*)(src + 4);
    o[0] = f2bf(v0.x * s); o[1] = f2bf(v0.y * s); o[2] = f2bf(v0.z * s); o[3] = f2bf(v0.w * s);
    o[4] = f2bf(v1.x * s); o[5] = f2bf(v1.y * s); o[6] = f2bf(v1.z * s); o[7] = f2bf(v1.w * s);
  }
  *(u16x8*)(a.sb[lvl] + (size_t)rl * KP + c * 8) = o;
}

// ---------------- W [CF][768] fp32 -> Wt [768][KP] bf16 transposed+swizzled ----------------
struct CwArgs { const float* w[5]; unsigned short* wt[5]; int CF[5]; int KP[5]; };

__global__ __launch_bounds__(256)
void conv_wt_k(CwArgs a) {
  int lvl = blockIdx.y;
  int KP = a.KP[lvl], CF = a.CF[lvl];
  int idx = blockIdx.x * 256 + threadIdx.x;
  if (idx >= 768 * (KP >> 3)) return;
  int c = idx / 768;
  int n = idx - c * 768;
  int w = c & 7, blk = c >> 3;
  int k0 = blk * 64 + ((w ^ (n & 7)) << 3);
  u16x8 o = {0, 0, 0, 0, 0, 0, 0, 0};
  if (k0 < CF) {
    const float* src = a.w[lvl] + (size_t)k0 * HID + n;
#pragma unroll
    for (int e = 0; e < 8; e++) o[e] = f2bf(src[(size_t)e * HID]);
  }
  *(u16x8*)(a.wt[lvl] + (size_t)n * KP + c * 8) = o;
}

// ---------------- bf16 MFMA GEMM: proj = segbf @ Wt^T + bias ----------------
// tile 128(M) x 64(N) x 64(K); 4 waves (2M x 2N); double-buffered LDS via global_load_lds
struct G2Args {
  const unsigned short* sb[5];
  const unsigned short* wt[5];
  const float* bias[5];
  float* proj;
  int KP[5];
  int KIT[5];
};

__global__ __launch_bounds__(256)
void gemm2_k(G2Args g) {
  int lvl = blockIdx.z;
  int n0 = blockIdx.x * 64;
  int m0 = blockIdx.y * 128;
  const char* A = (const char*)g.sb[lvl];
  const char* Bw = (const char*)g.wt[lvl];
  int KP = g.KP[lvl];
  int KIT = g.KIT[lvl];

  __shared__ char smem[49152];     // 2 x (16KB A + 8KB B)

  int t = threadIdx.x;
  int lane = t & 63;
  int w = t >> 6;
  int wm = w >> 1, wn = w & 1;

  f32x4 acc[4][2] = {};

  int rowb = t >> 3;               // 0..31
  int colb = (t & 7) * 16;         // 0..112

  auto stg = [&](int buf, int it) {
    char* base = smem + buf * 24576;
#pragma unroll
    for (int j = 0; j < 4; j++) {
      int row = j * 32 + rowb;
      gl_lds16(A + (size_t)(m0 + row) * (KP * 2) + it * 128 + colb,
               base + j * 4096 + t * 16);
    }
#pragma unroll
    for (int j = 0; j < 2; j++) {
      int row = j * 32 + rowb;
      gl_lds16(Bw + (size_t)(n0 + row) * (KP * 2) + it * 128 + colb,
               base + 16384 + j * 4096 + t * 16);
    }
  };

  int r15 = lane & 15, hi = lane >> 4, sx = (lane & 7) << 4;

  stg(0, 0);
  int cur = 0;
  for (int it = 0; it < KIT; ++it) {
    __syncthreads();                       // drains vmcnt: buf[cur] staged; prior reads done
    if (it + 1 < KIT) stg(cur ^ 1, it + 1);
    const char* base = smem + cur * 24576;
    s16x8 af[2][4]; s16x8 bf2[2][2];
#pragma unroll
    for (int s = 0; s < 2; s++) {
      int cb = (s * 64 + hi * 16) ^ sx;
#pragma unroll
      for (int fm = 0; fm < 4; fm++) {
        int row = wm * 64 + fm * 16 + r15;
        af[s][fm] = *(const s16x8*)(base + row * 128 + cb);
      }
#pragma unroll
      for (int fn = 0; fn < 2; fn++) {
        int row = wn * 32 + fn * 16 + r15;
        bf2[s][fn] = *(const s16x8*)(base + 16384 + row * 128 + cb);
      }
    }
#pragma unroll
    for (int s = 0; s < 2; s++)
#pragma unroll
      for (int fm = 0; fm < 4; fm++)
#pragma unroll
        for (int fn = 0; fn < 2; fn++)
          acc[fm][fn] = __builtin_amdgcn_mfma_f32_16x16x32_bf16(af[s][fm], bf2[s][fn], acc[fm][fn], 0, 0, 0);
    cur ^= 1;
  }

  const float* bias = g.bias[lvl];
  float* proj = g.proj + ((size_t)lvl * 1024 + m0) * HID;
#pragma unroll
  for (int fm = 0; fm < 4; fm++)
#pragma unroll
    for (int fn = 0; fn < 2; fn++) {
      int col = n0 + wn * 32 + fn * 16 + r15;
      int rb = wm * 64 + fm * 16 + hi * 4;
      float bi = bias[col];
      f32x4 v = acc[fm][fn];
#pragma unroll
      for (int r = 0; r < 4; r++)
        proj[(size_t)(rb + r) * HID + col] = v[r] + bi;
    }
}

// ---------------- LayerNorm over HID=768 (fp32 in/out) ----------------
struct LnArgs { const float* g[5]; const float* be[5]; };

__global__ __launch_bounds__(256)
void ln_k(LnArgs la, const float* __restrict__ proj, float* __restrict__ out) {
  int row = blockIdx.x;
  int lvl = row >> 10;
  const float* x = proj + (size_t)row * HID;
  int t = threadIdx.x;
  float v0 = x[t], v1 = x[t + 256], v2 = x[t + 512];
  float s = v0 + v1 + v2;
  float q = v0 * v0 + v1 * v1 + v2 * v2;
#pragma unroll
  for (int d = 32; d >= 1; d >>= 1) { s += __shfl_down(s, d); q += __shfl_down(q, d); }
  __shared__ float ps[4], pq[4];
  int w = t >> 6;
  if ((t & 63) == 0) { ps[w] = s; pq[w] = q; }
  __syncthreads();
  float S = ps[0] + ps[1] + ps[2] + ps[3];
  float Q = pq[0] + pq[1] + pq[2] + pq[3];
  float mean = S * (1.0f / HID);
  float var  = Q * (1.0f / HID) - mean * mean;
  float rs   = rsqrtf(var + 1e-5f);
  const float* g  = la.g[lvl];
  const float* be = la.be[lvl];
  float* o = out + (size_t)row * HID;
  o[t]       = (v0 - mean) * rs * g[t]       + be[t];
  o[t + 256] = (v1 - mean) * rs * g[t + 256] + be[t + 256];
  o[t + 512] = (v2 - mean) * rs * g[t + 512] + be[t + 512];
}

// =====================================================================
extern "C" void kernel_launch(void* const* d_in, const int* in_sizes, int n_in,
                              void* d_out, int out_size, void* d_ws, size_t ws_size,
                              hipStream_t stream) {
  static const int N_[5]  = {256, 1024, 4096, 16384, 65536};
  static const int CN_[5] = {512, 384, 192, 96, 48};
  static const int CF_[5] = {512, 896, 1088, 1184, 1232};
  static const int KP_[5] = {512, 896, 1088, 1216, 1280};   // CF rounded to 64
  static const int NC_[5] = {1, 1, 2, 4, 8};

  const float* x[5]; const int* p2s[5]; const float* W[5];
  const float* bias[5]; const float* g[5]; const float* be[5];
  for (int i = 0; i < 5; i++) {
    x[i]    = (const float*)d_in[6 * i + 0];
    p2s[i]  = (const int*)  d_in[6 * i + 1];
    W[i]    = (const float*)d_in[6 * i + 2];
    bias[i] = (const float*)d_in[6 * i + 3];
    g[i]    = (const float*)d_in[6 * i + 4];
    be[i]   = (const float*)d_in[6 * i + 5];
  }
  const int* inv[5] = {nullptr, (const int*)d_in[30], (const int*)d_in[31],
                       (const int*)d_in[32], (const int*)d_in[33]};

  int*   wsi = (int*)d_ws;
  float* wsf = (float*)d_ws;
  unsigned short* wsu = (unsigned short*)d_ws;

  // ---- workspace layout (f32-slot offsets unless noted) ----
  const int CNT = 0, CUR = 5120, OFS = 10240, SCL = 15360;
  static const int PT[5]   = {20480, 20992, 23040, 31232, 64000};          // end 195072
  const int CI20 = 195072, CI31 = 203264, CI30 = 236032;
  const int CI42 = 268800, CI41 = 399872, CI40 = 530944;                   // end 662016
  static const int SG[5]   = {662016, 1186304, 2103808, 3217920, 4430336}; // end 5691904
  // overlay (dead-SG reuse, strict stream order): WTBF then PROJ
  static const int WTu[5]  = {1324032, 1717248, 2405376, 3240960, 4174848};// ushort offs (= slot 662016*2)
  const int PROJ = 2578944;                                                // f32, 5*1024*768
  static const int SBu[5]  = {13022208, 13546496, 14464000, 15578112, 16823296}; // ushort (= slot 6511104*2)
  // total ws end = slot 9067008 (36.3 MB), proven budget 38.5 MB

  hipMemsetAsync(wsi + CNT, 0, (size_t)10240 * 4, stream);                        // cnt+cur
  hipMemsetAsync(wsf + SG[2], 0, (size_t)(5691904 - SG[2]) * 4, stream);          // chunked seg lvls

  auto nb = [](int tot) { return (tot + 255) / 256; };
  compose2_k<<<nb(2 * 4096),  256, 0, stream>>>(wsi + CI20, inv[2], inv[1], 2 * 4096);
  compose3_k<<<nb(2 * 16384), 256, 0, stream>>>(wsi + CI31, wsi + CI30, inv[3], inv[2], inv[1], 2 * 16384);
  compose4_k<<<nb(2 * 65536), 256, 0, stream>>>(wsi + CI42, wsi + CI41, wsi + CI40,
                                                inv[4], inv[3], inv[2], inv[1], 2 * 65536);

  for (int i = 0; i < 5; i++)
    hist_k<<<nb(2 * N_[i]), 256, 0, stream>>>(wsi + CNT + i * 1024, p2s[i], N_[i], 2 * N_[i]);

  scan_k<<<10, 512, 0, stream>>>(wsi + CNT, wsi + OFS, wsf + SCL);

  for (int i = 0; i < 5; i++)
    scat_k<<<nb(2 * N_[i]), 256, 0, stream>>>(wsi + PT[i], wsi + CUR + i * 1024,
                                              wsi + OFS + i * 1024, p2s[i], N_[i], 2 * N_[i]);

  const int* cimap[5][5] = {};
  cimap[1][0] = inv[1];
  cimap[2][1] = inv[2]; cimap[2][0] = wsi + CI20;
  cimap[3][2] = inv[3]; cimap[3][1] = wsi + CI31; cimap[3][0] = wsi + CI30;
  cimap[4][3] = inv[4]; cimap[4][2] = wsi + CI42; cimap[4][1] = wsi + CI41; cimap[4][0] = wsi + CI40;

  int offs[5][5] = {};
  for (int i = 1; i < 5; i++)
    for (int j = i - 1; j >= 0; j--) offs[i][j] = CN_[i] + offs[i - 1][j];

  for (int i = 0; i < 5; i++) {
    RedArgs ra{};
    int d = 0;
    for (int j = i; j >= 0; j--) {
      ra.x[d]   = x[j];
      ra.ci[d]  = (j == i) ? nullptr : cimap[i][j];
      ra.Nj[d]  = N_[j];
      ra.CN[d]  = CN_[j];
      ra.OFF[d] = offs[i][j];
      d++;
    }
    ra.nb = d; ra.N = N_[i]; ra.CF = CF_[i];
    dim3 grid(1024, NC_[i]);
    if (i <= 1)
      reduce2_k<1, false><<<grid, 256, 0, stream>>>(ra, wsi + PT[i], wsi + CNT + i * 1024,
                                                    wsi + OFS + i * 1024, wsf + SG[i], NC_[i]);
    else
      reduce2_k<2, true><<<grid, 256, 0, stream>>>(ra, wsi + PT[i], wsi + CNT + i * 1024,
                                                   wsi + OFS + i * 1024, wsf + SG[i], NC_[i]);
  }

  // seg -> bf16 (reads SG, writes SEGBF)
  CsArgs ca{};
  for (int i = 0; i < 5; i++) { ca.sg[i] = wsf + SG[i]; ca.sb[i] = wsu + SBu[i]; ca.CF[i] = CF_[i]; ca.KP[i] = KP_[i]; }
  ca.scl = wsf + SCL;
  conv_seg_k<<<5120, 256, 0, stream>>>(ca);

  // W -> bf16 transposed (writes WTBF over dead SG0/SG1 region; AFTER conv_seg)
  CwArgs cw{};
  for (int i = 0; i < 5; i++) { cw.w[i] = W[i]; cw.wt[i] = wsu + WTu[i]; cw.CF[i] = CF_[i]; cw.KP[i] = KP_[i]; }
  conv_wt_k<<<dim3(480, 5), 256, 0, stream>>>(cw);

  // MFMA GEMM
  G2Args ga{};
  for (int i = 0; i < 5; i++) {
    ga.sb[i] = wsu + SBu[i]; ga.wt[i] = wsu + WTu[i]; ga.bias[i] = bias[i];
    ga.KP[i] = KP_[i]; ga.KIT[i] = KP_[i] >> 6;
  }
  ga.proj = wsf + PROJ;
  gemm2_k<<<dim3(12, 8, 5), 256, 0, stream>>>(ga);

  LnArgs la{};
  for (int i = 0; i < 5; i++) { la.g[i] = g[i]; la.be[i] = be[i]; }
  ln_k<<<5120, 256, 0, stream>>>(la, wsf + PROJ, (float*)d_out);
}

// Round 5
// 242.676 us; speedup vs baseline: 3.2393x; 1.6809x over previous
//
#include <hip/hip_runtime.h>
#include <hip/hip_bf16.h>

#define NSEG 512
#define HID 768

typedef __attribute__((ext_vector_type(8))) short s16x8;
typedef __attribute__((ext_vector_type(8))) unsigned short u16x8;
typedef __attribute__((ext_vector_type(4))) unsigned short u16x4;
typedef __attribute__((ext_vector_type(4))) float f32x4;

__device__ __forceinline__ unsigned short f2bf(float x) {
  unsigned u = __builtin_bit_cast(unsigned, x);
  unsigned r = (u + 0x7fff + ((u >> 16) & 1)) >> 16;   // RNE
  return (unsigned short)r;
}

__device__ __forceinline__ float bf2f(unsigned short h) {
  unsigned u = ((unsigned)h) << 16;
  return __builtin_bit_cast(float, u);
}

__device__ __forceinline__ void gl_lds16(const void* g, void* l) {
  __builtin_amdgcn_global_load_lds(
      (const __attribute__((address_space(1))) unsigned*)g,
      (__attribute__((address_space(3))) unsigned*)l, 16, 0, 0);
}

// ---------------- fused index-compose chains ----------------
__global__ __launch_bounds__(256)
void compose4_k(int* __restrict__ c42, int* __restrict__ c41, int* __restrict__ c40,
                const int* __restrict__ inv4, const int* __restrict__ inv3,
                const int* __restrict__ inv2, const int* __restrict__ inv1, int total) {
  int t = blockIdx.x * 256 + threadIdx.x;
  if (t >= total) return;
  int b = (t >= 65536) ? 1 : 0;
  int n3 = inv4[t];
  int n2 = inv3[b * 16384 + n3]; c42[t] = n2;
  int n1 = inv2[b * 4096  + n2]; c41[t] = n1;
  int n0 = inv1[b * 1024  + n1]; c40[t] = n0;
}

__global__ __launch_bounds__(256)
void compose3_k(int* __restrict__ c31, int* __restrict__ c30,
                const int* __restrict__ inv3, const int* __restrict__ inv2,
                const int* __restrict__ inv1, int total) {
  int t = blockIdx.x * 256 + threadIdx.x;
  if (t >= total) return;
  int b = (t >= 16384) ? 1 : 0;
  int n2 = inv3[t];
  int n1 = inv2[b * 4096 + n2]; c31[t] = n1;
  int n0 = inv1[b * 1024 + n1]; c30[t] = n0;
}

__global__ __launch_bounds__(256)
void compose2_k(int* __restrict__ c20, const int* __restrict__ inv2,
                const int* __restrict__ inv1, int total) {
  int t = blockIdx.x * 256 + threadIdx.x;
  if (t >= total) return;
  int b = (t >= 4096) ? 1 : 0;
  c20[t] = inv1[b * 1024 + inv2[t]];
}

// ---------------- histogram ----------------
__global__ __launch_bounds__(256)
void hist_k(int* __restrict__ cnt, const int* __restrict__ p2s, int N, int total) {
  int t = blockIdx.x * 256 + threadIdx.x;
  if (t >= total) return;
  int b = (t >= N) ? 1 : 0;
  atomicAdd(&cnt[b * NSEG + p2s[t]], 1);
}

// ---------------- scan + 1/m ----------------
__global__ __launch_bounds__(512)
void scan_k(const int* __restrict__ cnt, int* __restrict__ off, float* __restrict__ scl) {
  __shared__ int sm[NSEG];
  int base = blockIdx.x * NSEG;
  int t = threadIdx.x;
  int v = cnt[base + t];
  sm[t] = v;
  __syncthreads();
  for (int d = 1; d < NSEG; d <<= 1) {
    int u = (t >= d) ? sm[t - d] : 0;
    __syncthreads();
    sm[t] += u;
    __syncthreads();
  }
  off[base + t] = sm[t] - v;
  scl[base + t] = 1.0f / (float)(v > 0 ? v : 1);
}

// ---------------- scatter point ids ----------------
__global__ __launch_bounds__(256)
void scat_k(int* __restrict__ pt, int* __restrict__ cur, const int* __restrict__ off,
            const int* __restrict__ p2s, int N, int total) {
  int t = blockIdx.x * 256 + threadIdx.x;
  if (t >= total) return;
  int b = (t >= N) ? 1 : 0;
  int n = t - b * N;
  int idx = b * NSEG + p2s[t];
  int pos = off[idx] + atomicAdd(&cur[idx], 1);
  pt[b * N + pos] = n;
}

// ---------------- segment-major SUM over cascaded feature blocks ----------------
// CHUNKED: each (row, chunk) block writes its full partial row to a PRIVATE
// bf16 buffer part[chunk][row][CF] — no atomics, no pre-zeroing anywhere.
struct RedArgs {
  const float* x[5];
  const int*   ci[5];
  int Nj[5];
  int CN[5];
  int OFF[5];
  int nb;
  int N;
  int CF;
};

template<int NK, bool CHUNKED>
__global__ __launch_bounds__(256)
void reduce2_k(RedArgs a, const int* __restrict__ pt, const int* __restrict__ cnt,
               const int* __restrict__ off, float* __restrict__ seg,
               unsigned short* __restrict__ part, int nchunk) {
  int bs = blockIdx.x;
  int b  = bs >> 9;
  int t  = threadIdx.x;
  int m  = cnt[bs];

  const float* xs[NK]; const int* cim[NK]; int str[NK]; bool val[NK];
#pragma unroll
  for (int k = 0; k < NK; k++) {
    int c4 = (t + k * 256) * 4;
    val[k] = c4 < a.CF;
    xs[k] = nullptr; cim[k] = nullptr; str[k] = 1;
    if (val[k]) {
      int j = 0;
      while (j < a.nb - 1 && !(c4 >= a.OFF[j] && c4 < a.OFF[j] + a.CN[j])) j++;
      xs[k]  = a.x[j] + (size_t)b * a.Nj[j] * a.CN[j] + (c4 - a.OFF[j]);
      cim[k] = a.ci[j] ? (a.ci[j] + (size_t)b * a.N) : nullptr;
      str[k] = a.CN[j];
    }
  }

  int start = 0, end = m;
  if (CHUNKED) {
    int cs = (m + nchunk - 1) / nchunk;
    start = blockIdx.y * cs;
    end = min(m, start + cs);
  } else {
    if (m == 0) {
      float* so = seg + (size_t)bs * a.CF;
#pragma unroll
      for (int k = 0; k < NK; k++)
        if (val[k]) *(float4*)(so + (t + k * 256) * 4) = make_float4(0.f, 0.f, 0.f, 0.f);
      return;
    }
  }

  float ax[NK][4] = {};
  if (start < end) {
    const int* pl = pt + (size_t)b * a.N + off[bs];
    int p = start;
    for (; p + 4 <= end; p += 4) {
      int n0 = pl[p], n1 = pl[p + 1], n2 = pl[p + 2], n3 = pl[p + 3];
#pragma unroll
      for (int k = 0; k < NK; k++) if (val[k]) {
        int r0 = cim[k] ? cim[k][n0] : n0;
        int r1 = cim[k] ? cim[k][n1] : n1;
        int r2 = cim[k] ? cim[k][n2] : n2;
        int r3 = cim[k] ? cim[k][n3] : n3;
        float4 v0 = *(const float4*)(xs[k] + (size_t)r0 * str[k]);
        float4 v1 = *(const float4*)(xs[k] + (size_t)r1 * str[k]);
        float4 v2 = *(const float4*)(xs[k] + (size_t)r2 * str[k]);
        float4 v3 = *(const float4*)(xs[k] + (size_t)r3 * str[k]);
        ax[k][0] += (v0.x + v1.x) + (v2.x + v3.x);
        ax[k][1] += (v0.y + v1.y) + (v2.y + v3.y);
        ax[k][2] += (v0.z + v1.z) + (v2.z + v3.z);
        ax[k][3] += (v0.w + v1.w) + (v2.w + v3.w);
      }
    }
    for (; p < end; p++) {
      int n0 = pl[p];
#pragma unroll
      for (int k = 0; k < NK; k++) if (val[k]) {
        int r0 = cim[k] ? cim[k][n0] : n0;
        float4 v0 = *(const float4*)(xs[k] + (size_t)r0 * str[k]);
        ax[k][0] += v0.x; ax[k][1] += v0.y; ax[k][2] += v0.z; ax[k][3] += v0.w;
      }
    }
  }

  if (CHUNKED) {
    unsigned short* po = part + ((size_t)blockIdx.y * 1024 + bs) * a.CF;
#pragma unroll
    for (int k = 0; k < NK; k++) if (val[k]) {
      int c4 = (t + k * 256) * 4;
      u16x4 o = {f2bf(ax[k][0]), f2bf(ax[k][1]), f2bf(ax[k][2]), f2bf(ax[k][3])};
      *(u16x4*)(po + c4) = o;
    }
  } else {
    float* so = seg + (size_t)bs * a.CF;
#pragma unroll
    for (int k = 0; k < NK; k++) if (val[k]) {
      int c4 = (t + k * 256) * 4;
      *(float4*)(so + c4) = make_float4(ax[k][0], ax[k][1], ax[k][2], ax[k][3]);
    }
  }
}

// ---------------- combine partials + scale + bf16 + chunk-swizzle + K-pad ----------------
// stored chunk c (16B) of row r = orig chunk (c&7)^(r&7) within each 64-elem k-block
struct CsArgs {
  const float* sg[2];              // levels 0,1: fp32 seg sums
  const unsigned short* pp[5];     // levels 2..4: bf16 partials [NC][1024][CF]
  unsigned short* sb[5];
  const float* scl;
  int CF[5]; int KP[5]; int NC[5];
};

__global__ __launch_bounds__(256)
void conv_seg_k(CsArgs a) {
  int row = blockIdx.x;            // 0..5119
  int lvl = row >> 10;
  int rl  = row & 1023;
  int CF = a.CF[lvl], KP = a.KP[lvl];
  int c = threadIdx.x;
  if (c >= (KP >> 3)) return;
  float s = a.scl[row];
  int w = c & 7, blk = c >> 3;
  int k0 = blk * 64 + ((w ^ (rl & 7)) << 3);
  u16x8 o = {0, 0, 0, 0, 0, 0, 0, 0};
  if (k0 < CF) {
    float acc[8] = {};
    if (lvl <= 1) {
      const float* src = a.sg[lvl] + (size_t)rl * CF + k0;
      float4 v0 = *(const float4*)src;
      float4 v1 = *(const float4*)(src + 4);
      acc[0] = v0.x; acc[1] = v0.y; acc[2] = v0.z; acc[3] = v0.w;
      acc[4] = v1.x; acc[5] = v1.y; acc[6] = v1.z; acc[7] = v1.w;
    } else {
      int nc = a.NC[lvl];
      const unsigned short* base = a.pp[lvl] + (size_t)rl * CF + k0;
      for (int n = 0; n < nc; n++) {
        u16x8 v = *(const u16x8*)(base + (size_t)n * 1024 * CF);
#pragma unroll
        for (int e = 0; e < 8; e++) acc[e] += bf2f(v[e]);
      }
    }
#pragma unroll
    for (int e = 0; e < 8; e++) o[e] = f2bf(acc[e] * s);
  }
  *(u16x8*)(a.sb[lvl] + (size_t)rl * KP + c * 8) = o;
}

// ---------------- W [CF][768] fp32 -> Wt [768][KP] bf16 transposed+swizzled ----------------
struct CwArgs { const float* w[5]; unsigned short* wt[5]; int CF[5]; int KP[5]; };

__global__ __launch_bounds__(256)
void conv_wt_k(CwArgs a) {
  int lvl = blockIdx.y;
  int KP = a.KP[lvl], CF = a.CF[lvl];
  int idx = blockIdx.x * 256 + threadIdx.x;
  if (idx >= 768 * (KP >> 3)) return;
  int c = idx / 768;
  int n = idx - c * 768;
  int w = c & 7, blk = c >> 3;
  int k0 = blk * 64 + ((w ^ (n & 7)) << 3);
  u16x8 o = {0, 0, 0, 0, 0, 0, 0, 0};
  if (k0 < CF) {
    const float* src = a.w[lvl] + (size_t)k0 * HID + n;
#pragma unroll
    for (int e = 0; e < 8; e++) o[e] = f2bf(src[(size_t)e * HID]);
  }
  *(u16x8*)(a.wt[lvl] + (size_t)n * KP + c * 8) = o;
}

// ---------------- bf16 MFMA GEMM: proj = segbf @ Wt^T + bias ----------------
struct G2Args {
  const unsigned short* sb[5];
  const unsigned short* wt[5];
  const float* bias[5];
  float* proj;
  int KP[5];
  int KIT[5];
};

__global__ __launch_bounds__(256)
void gemm2_k(G2Args g) {
  int lvl = blockIdx.z;
  int n0 = blockIdx.x * 64;
  int m0 = blockIdx.y * 128;
  const char* A = (const char*)g.sb[lvl];
  const char* Bw = (const char*)g.wt[lvl];
  int KP = g.KP[lvl];
  int KIT = g.KIT[lvl];

  __shared__ char smem[49152];     // 2 x (16KB A + 8KB B)

  int t = threadIdx.x;
  int lane = t & 63;
  int w = t >> 6;
  int wm = w >> 1, wn = w & 1;

  f32x4 acc[4][2] = {};

  int rowb = t >> 3;
  int colb = (t & 7) * 16;

  auto stg = [&](int buf, int it) {
    char* base = smem + buf * 24576;
#pragma unroll
    for (int j = 0; j < 4; j++) {
      int row = j * 32 + rowb;
      gl_lds16(A + (size_t)(m0 + row) * (KP * 2) + it * 128 + colb,
               base + j * 4096 + t * 16);
    }
#pragma unroll
    for (int j = 0; j < 2; j++) {
      int row = j * 32 + rowb;
      gl_lds16(Bw + (size_t)(n0 + row) * (KP * 2) + it * 128 + colb,
               base + 16384 + j * 4096 + t * 16);
    }
  };

  int r15 = lane & 15, hi = lane >> 4, sx = (lane & 7) << 4;

  stg(0, 0);
  int cur = 0;
  for (int it = 0; it < KIT; ++it) {
    __syncthreads();
    if (it + 1 < KIT) stg(cur ^ 1, it + 1);
    const char* base = smem + cur * 24576;
    s16x8 af[2][4]; s16x8 bf2[2][2];
#pragma unroll
    for (int s = 0; s < 2; s++) {
      int cb = (s * 64 + hi * 16) ^ sx;
#pragma unroll
      for (int fm = 0; fm < 4; fm++) {
        int row = wm * 64 + fm * 16 + r15;
        af[s][fm] = *(const s16x8*)(base + row * 128 + cb);
      }
#pragma unroll
      for (int fn = 0; fn < 2; fn++) {
        int row = wn * 32 + fn * 16 + r15;
        bf2[s][fn] = *(const s16x8*)(base + 16384 + row * 128 + cb);
      }
    }
#pragma unroll
    for (int s = 0; s < 2; s++)
#pragma unroll
      for (int fm = 0; fm < 4; fm++)
#pragma unroll
        for (int fn = 0; fn < 2; fn++)
          acc[fm][fn] = __builtin_amdgcn_mfma_f32_16x16x32_bf16(af[s][fm], bf2[s][fn], acc[fm][fn], 0, 0, 0);
    cur ^= 1;
  }

  const float* bias = g.bias[lvl];
  float* proj = g.proj + ((size_t)lvl * 1024 + m0) * HID;
#pragma unroll
  for (int fm = 0; fm < 4; fm++)
#pragma unroll
    for (int fn = 0; fn < 2; fn++) {
      int col = n0 + wn * 32 + fn * 16 + r15;
      int rb = wm * 64 + fm * 16 + hi * 4;
      float bi = bias[col];
      f32x4 v = acc[fm][fn];
#pragma unroll
      for (int r = 0; r < 4; r++)
        proj[(size_t)(rb + r) * HID + col] = v[r] + bi;
    }
}

// ---------------- LayerNorm over HID=768 (fp32 in/out) ----------------
struct LnArgs { const float* g[5]; const float* be[5]; };

__global__ __launch_bounds__(256)
void ln_k(LnArgs la, const float* __restrict__ proj, float* __restrict__ out) {
  int row = blockIdx.x;
  int lvl = row >> 10;
  const float* x = proj + (size_t)row * HID;
  int t = threadIdx.x;
  float v0 = x[t], v1 = x[t + 256], v2 = x[t + 512];
  float s = v0 + v1 + v2;
  float q = v0 * v0 + v1 * v1 + v2 * v2;
#pragma unroll
  for (int d = 32; d >= 1; d >>= 1) { s += __shfl_down(s, d); q += __shfl_down(q, d); }
  __shared__ float ps[4], pq[4];
  int w = t >> 6;
  if ((t & 63) == 0) { ps[w] = s; pq[w] = q; }
  __syncthreads();
  float S = ps[0] + ps[1] + ps[2] + ps[3];
  float Q = pq[0] + pq[1] + pq[2] + pq[3];
  float mean = S * (1.0f / HID);
  float var  = Q * (1.0f / HID) - mean * mean;
  float rs   = rsqrtf(var + 1e-5f);
  const float* g  = la.g[lvl];
  const float* be = la.be[lvl];
  float* o = out + (size_t)row * HID;
  o[t]       = (v0 - mean) * rs * g[t]       + be[t];
  o[t + 256] = (v1 - mean) * rs * g[t + 256] + be[t + 256];
  o[t + 512] = (v2 - mean) * rs * g[t + 512] + be[t + 512];
}

// =====================================================================
extern "C" void kernel_launch(void* const* d_in, const int* in_sizes, int n_in,
                              void* d_out, int out_size, void* d_ws, size_t ws_size,
                              hipStream_t stream) {
  static const int N_[5]  = {256, 1024, 4096, 16384, 65536};
  static const int CN_[5] = {512, 384, 192, 96, 48};
  static const int CF_[5] = {512, 896, 1088, 1184, 1232};
  static const int KP_[5] = {512, 896, 1088, 1216, 1280};   // CF rounded to 64
  static const int NC_[5] = {1, 1, 2, 2, 4};                // point-chunks (no atomics)

  const float* x[5]; const int* p2s[5]; const float* W[5];
  const float* bias[5]; const float* g[5]; const float* be[5];
  for (int i = 0; i < 5; i++) {
    x[i]    = (const float*)d_in[6 * i + 0];
    p2s[i]  = (const int*)  d_in[6 * i + 1];
    W[i]    = (const float*)d_in[6 * i + 2];
    bias[i] = (const float*)d_in[6 * i + 3];
    g[i]    = (const float*)d_in[6 * i + 4];
    be[i]   = (const float*)d_in[6 * i + 5];
  }
  const int* inv[5] = {nullptr, (const int*)d_in[30], (const int*)d_in[31],
                       (const int*)d_in[32], (const int*)d_in[33]};

  int*   wsi = (int*)d_ws;
  float* wsf = (float*)d_ws;
  unsigned short* wsu = (unsigned short*)d_ws;

  // ---- workspace layout ----
  // f32-slot offsets:
  const int CNT = 0, CUR = 5120, OFS = 10240, SCL = 15360;
  static const int PT[5]   = {20480, 20992, 23040, 31232, 64000};          // end 195072
  const int CI20 = 195072, CI31 = 203264, CI30 = 236032;
  const int CI42 = 268800, CI41 = 399872, CI40 = 530944;                   // end 662016
  static const int SG01[2] = {662016, 1186304};                            // fp32 seg lvl0/1, end 2103808
  // u16 offsets:
  static const int PPu[5]  = {0, 0, 4207616, 6435840, 8860672};            // bf16 partials lvl2/3/4
  static const int SBu[5]  = {13906944, 14431232, 15348736, 16462848, 17708032}; // end 19018752 (38.04 MB)
  // overlays (dead regions, strict stream order):
  static const int WTu[5]  = {1324032, 1717248, 2405376, 3240960, 4174848};// over SG01, end u16 5157888
  const int PROJ = 2578944;                                                // f32, over partials, end slot 6511104

  hipMemsetAsync(wsi + CNT, 0, (size_t)10240 * 4, stream);   // cnt + cur only

  auto nb = [](int tot) { return (tot + 255) / 256; };
  compose2_k<<<nb(2 * 4096),  256, 0, stream>>>(wsi + CI20, inv[2], inv[1], 2 * 4096);
  compose3_k<<<nb(2 * 16384), 256, 0, stream>>>(wsi + CI31, wsi + CI30, inv[3], inv[2], inv[1], 2 * 16384);
  compose4_k<<<nb(2 * 65536), 256, 0, stream>>>(wsi + CI42, wsi + CI41, wsi + CI40,
                                                inv[4], inv[3], inv[2], inv[1], 2 * 65536);

  for (int i = 0; i < 5; i++)
    hist_k<<<nb(2 * N_[i]), 256, 0, stream>>>(wsi + CNT + i * 1024, p2s[i], N_[i], 2 * N_[i]);

  scan_k<<<10, 512, 0, stream>>>(wsi + CNT, wsi + OFS, wsf + SCL);

  for (int i = 0; i < 5; i++)
    scat_k<<<nb(2 * N_[i]), 256, 0, stream>>>(wsi + PT[i], wsi + CUR + i * 1024,
                                              wsi + OFS + i * 1024, p2s[i], N_[i], 2 * N_[i]);

  const int* cimap[5][5] = {};
  cimap[1][0] = inv[1];
  cimap[2][1] = inv[2]; cimap[2][0] = wsi + CI20;
  cimap[3][2] = inv[3]; cimap[3][1] = wsi + CI31; cimap[3][0] = wsi + CI30;
  cimap[4][3] = inv[4]; cimap[4][2] = wsi + CI42; cimap[4][1] = wsi + CI41; cimap[4][0] = wsi + CI40;

  int offs[5][5] = {};
  for (int i = 1; i < 5; i++)
    for (int j = i - 1; j >= 0; j--) offs[i][j] = CN_[i] + offs[i - 1][j];

  for (int i = 0; i < 5; i++) {
    RedArgs ra{};
    int d = 0;
    for (int j = i; j >= 0; j--) {
      ra.x[d]   = x[j];
      ra.ci[d]  = (j == i) ? nullptr : cimap[i][j];
      ra.Nj[d]  = N_[j];
      ra.CN[d]  = CN_[j];
      ra.OFF[d] = offs[i][j];
      d++;
    }
    ra.nb = d; ra.N = N_[i]; ra.CF = CF_[i];
    dim3 grid(1024, NC_[i]);
    if (i <= 1)
      reduce2_k<1, false><<<grid, 256, 0, stream>>>(ra, wsi + PT[i], wsi + CNT + i * 1024,
                                                    wsi + OFS + i * 1024, wsf + SG01[i],
                                                    nullptr, NC_[i]);
    else
      reduce2_k<2, true><<<grid, 256, 0, stream>>>(ra, wsi + PT[i], wsi + CNT + i * 1024,
                                                   wsi + OFS + i * 1024, nullptr,
                                                   wsu + PPu[i], NC_[i]);
  }

  // combine partials -> scaled bf16 seg (swizzled, K-padded)
  CsArgs ca{};
  ca.sg[0] = wsf + SG01[0]; ca.sg[1] = wsf + SG01[1];
  for (int i = 0; i < 5; i++) {
    ca.pp[i] = (i >= 2) ? (wsu + PPu[i]) : nullptr;
    ca.sb[i] = wsu + SBu[i];
    ca.CF[i] = CF_[i]; ca.KP[i] = KP_[i]; ca.NC[i] = NC_[i];
  }
  ca.scl = wsf + SCL;
  conv_seg_k<<<5120, 256, 0, stream>>>(ca);

  // W -> bf16 transposed (over dead SG01 region; AFTER conv_seg)
  CwArgs cw{};
  for (int i = 0; i < 5; i++) { cw.w[i] = W[i]; cw.wt[i] = wsu + WTu[i]; cw.CF[i] = CF_[i]; cw.KP[i] = KP_[i]; }
  conv_wt_k<<<dim3(480, 5), 256, 0, stream>>>(cw);

  // MFMA GEMM (writes PROJ over dead partials region)
  G2Args ga{};
  for (int i = 0; i < 5; i++) {
    ga.sb[i] = wsu + SBu[i]; ga.wt[i] = wsu + WTu[i]; ga.bias[i] = bias[i];
    ga.KP[i] = KP_[i]; ga.KIT[i] = KP_[i] >> 6;
  }
  ga.proj = wsf + PROJ;
  gemm2_k<<<dim3(12, 8, 5), 256, 0, stream>>>(ga);

  LnArgs la{};
  for (int i = 0; i < 5; i++) { la.g[i] = g[i]; la.be[i] = be[i]; }
  ln_k<<<5120, 256, 0, stream>>>(la, wsf + PROJ, (float*)d_out);
}